// Round 1
// baseline (3593.552 us; speedup 1.0000x reference)
//
#include <hip/hip_runtime.h>

#define N_NODES 100000
#define N_EDGES 6400000
#define IN_DIM 10
#define HIDDEN 16

// Kernel 1: one thread per edge; atomically accumulate x[src] into summed[dst]
// and bump counts[dst]. x is 4 MB -> gathers hit L2/L3. summed is 4 MB -> atomics
// land in L2.
__global__ void sage_scatter(const float* __restrict__ x,
                             const int* __restrict__ src,
                             const int* __restrict__ dst,
                             float* __restrict__ summed,
                             float* __restrict__ counts) {
    int e = blockIdx.x * blockDim.x + threadIdx.x;
    if (e >= N_EDGES) return;
    int s = src[e];
    int d = dst[e];
    // defensive: skip malformed indices rather than corrupt memory
    if ((unsigned)s >= N_NODES || (unsigned)d >= N_NODES) return;
    const float* xs = x + (size_t)s * IN_DIM;
    float* sm = summed + (size_t)d * IN_DIM;
    float v[IN_DIM];
#pragma unroll
    for (int k = 0; k < IN_DIM; ++k) v[k] = xs[k];
#pragma unroll
    for (int k = 0; k < IN_DIM; ++k) atomicAdd(&sm[k], v[k]);
    atomicAdd(&counts[d], 1.0f);
}

// Kernel 2: one thread per (node, hidden) output element.
// Threads in a group of 16 share the node -> summed/x reads broadcast;
// out writes fully coalesced. Weights staged in LDS.
__global__ void sage_out(const float* __restrict__ x,
                         const float* __restrict__ summed,
                         const float* __restrict__ counts,
                         const float* __restrict__ W_l,
                         const float* __restrict__ b_l,
                         const float* __restrict__ W_r,
                         float* __restrict__ out) {
    __shared__ float sWl[IN_DIM * HIDDEN];
    __shared__ float sWr[IN_DIM * HIDDEN];
    __shared__ float sb[HIDDEN];
    int t = threadIdx.x;
    if (t < IN_DIM * HIDDEN) {
        sWl[t] = W_l[t];
        sWr[t] = W_r[t];
    }
    if (t < HIDDEN) sb[t] = b_l[t];
    __syncthreads();

    int tid = blockIdx.x * blockDim.x + t;
    if (tid >= N_NODES * HIDDEN) return;
    int node = tid >> 4;      // /HIDDEN
    int h = tid & (HIDDEN - 1);

    float inv = 1.0f / fmaxf(counts[node], 1.0f);
    const float* sm = summed + (size_t)node * IN_DIM;
    const float* xr = x + (size_t)node * IN_DIM;

    float acc = sb[h];
#pragma unroll
    for (int k = 0; k < IN_DIM; ++k) {
        acc += sm[k] * inv * sWl[k * HIDDEN + h];
        acc += xr[k] * sWr[k * HIDDEN + h];
    }
    out[tid] = acc;
}

extern "C" void kernel_launch(void* const* d_in, const int* in_sizes, int n_in,
                              void* d_out, int out_size, void* d_ws, size_t ws_size,
                              hipStream_t stream) {
    const float* x   = (const float*)d_in[0];
    const int*   ei  = (const int*)d_in[1];   // [2, E] flat: first E = src, next E = dst
    const float* W_l = (const float*)d_in[2];
    const float* b_l = (const float*)d_in[3];
    const float* W_r = (const float*)d_in[4];
    float* out = (float*)d_out;

    float* summed = (float*)d_ws;                    // [N_NODES * IN_DIM]
    float* counts = summed + (size_t)N_NODES * IN_DIM; // [N_NODES]

    // ws is re-poisoned to 0xAA before every timed launch -> must zero each call.
    hipMemsetAsync(d_ws, 0, (size_t)(N_NODES * IN_DIM + N_NODES) * sizeof(float), stream);

    int threads = 256;
    int eblocks = (N_EDGES + threads - 1) / threads;
    sage_scatter<<<eblocks, threads, 0, stream>>>(x, ei, ei + N_EDGES, summed, counts);

    int oblocks = (N_NODES * HIDDEN + threads - 1) / threads;
    sage_out<<<oblocks, threads, 0, stream>>>(x, summed, counts, W_l, b_l, W_r, out);
}

// Round 2
// 676.422 us; speedup vs baseline: 5.3126x; 5.3126x over previous
//
#include <hip/hip_runtime.h>

#define N_NODES 100000
#define N_EDGES 6400000
#define IN_DIM 10
#define HIDDEN 16
#define CAP 128   // slots/node; Poisson(64) => P(deg>128) ~ 5e-13/node; spill path covers it

// ---------------- fast path: counting-sort CSR + atomic-free gather ----------------

// K1: one int atomic per edge -> slot in fixed-stride CSR of src ids.
__global__ void build_csr(const int* __restrict__ src, const int* __restrict__ dst,
                          const float* __restrict__ x,
                          int* __restrict__ cnt, int* __restrict__ csr,
                          float* __restrict__ spill) {
    int e = blockIdx.x * blockDim.x + threadIdx.x;
    if (e >= N_EDGES) return;
    int s = src[e], d = dst[e];
    if ((unsigned)s >= N_NODES || (unsigned)d >= N_NODES) return;
    int slot = atomicAdd(&cnt[d], 1);
    if (slot < CAP) {
        csr[(size_t)d * CAP + slot] = s;
    } else {
        // astronomically rare; keep exact semantics
        const float* xs = x + (size_t)s * IN_DIM;
#pragma unroll
        for (int k = 0; k < IN_DIM; ++k) atomicAdd(&spill[(size_t)d * IN_DIM + k], xs[k]);
    }
}

// K2: one wave per node. Gather x[src] rows (L2-resident), reduce across lanes,
// fused mean + GEMV epilogue. No atomics.
__global__ void gather_out(const float* __restrict__ x, const int* __restrict__ cnt,
                           const int* __restrict__ csr, const float* __restrict__ spill,
                           const float* __restrict__ W_l, const float* __restrict__ b_l,
                           const float* __restrict__ W_r, float* __restrict__ out) {
    __shared__ float sWl[IN_DIM * HIDDEN], sWr[IN_DIM * HIDDEN], sb[HIDDEN];
    int t = threadIdx.x;
    if (t < IN_DIM * HIDDEN) { sWl[t] = W_l[t]; sWr[t] = W_r[t]; }
    if (t < HIDDEN) sb[t] = b_l[t];
    __syncthreads();

    int wave = t >> 6, lane = t & 63;
    int n = blockIdx.x * (blockDim.x >> 6) + wave;
    if (n >= N_NODES) return;

    int deg = cnt[n];
    int in_csr = min(deg, CAP);

    float acc[IN_DIM];
#pragma unroll
    for (int k = 0; k < IN_DIM; ++k) acc[k] = 0.0f;

    for (int i = lane; i < in_csr; i += 64) {
        int s = csr[(size_t)n * CAP + i];            // coalesced across lanes
        const float* xs = x + (size_t)s * IN_DIM;    // random 40B row, L1/L2 hit
#pragma unroll
        for (int k = 0; k < IN_DIM; ++k) acc[k] += xs[k];
    }

    // butterfly reduction across the 64-lane wave
#pragma unroll
    for (int off = 32; off > 0; off >>= 1) {
#pragma unroll
        for (int k = 0; k < IN_DIM; ++k) acc[k] += __shfl_xor(acc[k], off, 64);
    }

    float inv = 1.0f / fmaxf((float)deg, 1.0f);
    if (lane < HIDDEN) {
        int h = lane;
        const float* xr = x + (size_t)n * IN_DIM;
        float o = sb[h];
#pragma unroll
        for (int k = 0; k < IN_DIM; ++k) {
            float m = (acc[k] + spill[(size_t)n * IN_DIM + k]) * inv;
            o += m * sWl[k * HIDDEN + h] + xr[k] * sWr[k * HIDDEN + h];
        }
        out[(size_t)n * HIDDEN + h] = o;   // 16 contiguous floats per node
    }
}

// ---------------- fallback path (round-1, correct, slow) for small ws ----------------

__global__ void sage_scatter_fb(const float* __restrict__ x,
                                const int* __restrict__ src,
                                const int* __restrict__ dst,
                                float* __restrict__ summed,
                                float* __restrict__ counts) {
    int e = blockIdx.x * blockDim.x + threadIdx.x;
    if (e >= N_EDGES) return;
    int s = src[e], d = dst[e];
    if ((unsigned)s >= N_NODES || (unsigned)d >= N_NODES) return;
    const float* xs = x + (size_t)s * IN_DIM;
    float* sm = summed + (size_t)d * IN_DIM;
#pragma unroll
    for (int k = 0; k < IN_DIM; ++k) atomicAdd(&sm[k], xs[k]);
    atomicAdd(&counts[d], 1.0f);
}

__global__ void sage_out_fb(const float* __restrict__ x,
                            const float* __restrict__ summed,
                            const float* __restrict__ counts,
                            const float* __restrict__ W_l,
                            const float* __restrict__ b_l,
                            const float* __restrict__ W_r,
                            float* __restrict__ out) {
    __shared__ float sWl[IN_DIM * HIDDEN], sWr[IN_DIM * HIDDEN], sb[HIDDEN];
    int t = threadIdx.x;
    if (t < IN_DIM * HIDDEN) { sWl[t] = W_l[t]; sWr[t] = W_r[t]; }
    if (t < HIDDEN) sb[t] = b_l[t];
    __syncthreads();
    int tid = blockIdx.x * blockDim.x + t;
    if (tid >= N_NODES * HIDDEN) return;
    int node = tid >> 4, h = tid & (HIDDEN - 1);
    float inv = 1.0f / fmaxf(counts[node], 1.0f);
    const float* sm = summed + (size_t)node * IN_DIM;
    const float* xr = x + (size_t)node * IN_DIM;
    float acc = sb[h];
#pragma unroll
    for (int k = 0; k < IN_DIM; ++k)
        acc += sm[k] * inv * sWl[k * HIDDEN + h] + xr[k] * sWr[k * HIDDEN + h];
    out[tid] = acc;
}

extern "C" void kernel_launch(void* const* d_in, const int* in_sizes, int n_in,
                              void* d_out, int out_size, void* d_ws, size_t ws_size,
                              hipStream_t stream) {
    const float* x   = (const float*)d_in[0];
    const int*   ei  = (const int*)d_in[1];   // [2, E] flat: first E = src, next E = dst
    const float* W_l = (const float*)d_in[2];
    const float* b_l = (const float*)d_in[3];
    const float* W_r = (const float*)d_in[4];
    float* out = (float*)d_out;
    const int* src = ei;
    const int* dst = ei + N_EDGES;

    const size_t need = ((size_t)N_NODES            // cnt (ints)
                       + (size_t)N_NODES * IN_DIM   // spill (floats)
                       + (size_t)N_NODES * CAP)     // csr (ints)
                       * 4;

    int threads = 256;
    if (ws_size >= need) {
        int*   cnt   = (int*)d_ws;
        float* spill = (float*)(cnt + N_NODES);
        int*   csr   = (int*)(spill + (size_t)N_NODES * IN_DIM);

        // cnt + spill must be zero every call (ws re-poisoned to 0xAA)
        hipMemsetAsync(d_ws, 0, (size_t)(N_NODES + N_NODES * IN_DIM) * 4, stream);

        int eblocks = (N_EDGES + threads - 1) / threads;
        build_csr<<<eblocks, threads, 0, stream>>>(src, dst, x, cnt, csr, spill);

        int waves_per_block = threads / 64;
        int nblocks = (N_NODES + waves_per_block - 1) / waves_per_block;
        gather_out<<<nblocks, threads, 0, stream>>>(x, cnt, csr, spill, W_l, b_l, W_r, out);
    } else {
        float* summed = (float*)d_ws;
        float* counts = summed + (size_t)N_NODES * IN_DIM;
        hipMemsetAsync(d_ws, 0, (size_t)(N_NODES * IN_DIM + N_NODES) * sizeof(float), stream);
        int eblocks = (N_EDGES + threads - 1) / threads;
        sage_scatter_fb<<<eblocks, threads, 0, stream>>>(x, src, dst, summed, counts);
        int oblocks = (N_NODES * HIDDEN + threads - 1) / threads;
        sage_out_fb<<<oblocks, threads, 0, stream>>>(x, summed, counts, W_l, b_l, W_r, out);
    }
}

// Round 3
// 573.554 us; speedup vs baseline: 6.2654x; 1.1794x over previous
//
#include <hip/hip_runtime.h>

#define N_NODES 100000
#define N_EDGES 6400000
#define IN_DIM 10
#define HIDDEN 16

#define BKT_SHIFT 8
#define BKT_NODES 256                       // nodes per bucket
#define NBKT 391                            // ceil(100000/256)
#define RBIN 38                             // LDS slots per (block,bucket) in pass 1
#define EPB 10240                           // edges per pass-1 block (mean fill 26.2/bin)
#define NB1 ((N_EDGES + EPB - 1) / EPB)     // 625 blocks
#define CAPB 18432                          // region slots per bucket (mean 16368, +16 sd)

// Pass 1: bin edges by dst bucket. Packed record: src (17b) | local-dst (8b) -> 4 B.
// Per-edge cost is one LDS atomic + one LDS store. Device-scope returning atomics
// only at drain time: one per (block, nonempty bucket) ~ 244k total (vs 6.4M in R2).
// Drain writes are per-lane sequential dwords into a contiguous run -> L2
// write-combines into full-line writebacks.
__global__ __launch_bounds__(512) void bin_edges(const int* __restrict__ src,
                                                 const int* __restrict__ dst,
                                                 int* __restrict__ gcur,
                                                 unsigned* __restrict__ region) {
    __shared__ int lcur[NBKT];
    __shared__ unsigned lbin[NBKT * RBIN];   // 59.4 KB
    for (int b = threadIdx.x; b < NBKT; b += 512) lcur[b] = 0;
    __syncthreads();

    int base = blockIdx.x * EPB;
    int end = min(base + EPB, N_EDGES);
    for (int i = base + (int)threadIdx.x; i < end; i += 512) {
        int s = src[i], d = dst[i];
        if ((unsigned)s >= N_NODES || (unsigned)d >= N_NODES) continue;
        unsigned pack = (unsigned)s | ((unsigned)(d & (BKT_NODES - 1)) << 17);
        int b = d >> BKT_SHIFT;
        int pos = atomicAdd(&lcur[b], 1);            // LDS atomic (cheap)
        if (pos < RBIN) {
            lbin[b * RBIN + pos] = pack;
        } else {
            // rare overflow (~1e-2 per bin-block tail): direct device scatter
            int g = atomicAdd(&gcur[b], 1);
            if (g < CAPB) region[(size_t)b * CAPB + g] = pack;
        }
    }
    __syncthreads();

    // drain: one device atomic per nonempty bin, contiguous run write
    for (int b = threadIdx.x; b < NBKT; b += 512) {
        int f = min(lcur[b], RBIN);
        if (f > 0) {
            int g = atomicAdd(&gcur[b], f);
            unsigned* dp = region + (size_t)b * CAPB;
#pragma unroll 4
            for (int j = 0; j < f; ++j) {
                int gg = g + j;
                if (gg < CAPB) dp[gg] = lbin[b * RBIN + j];
            }
        }
    }
}

// Pass 2: one block per bucket. Atomic-free at device scope: accumulate into LDS
// (row stride 11, coprime with 32 banks), then fused mean + GEMV + bias epilogue.
__global__ __launch_bounds__(512) void bucket_out(const float* __restrict__ x,
                                                  const int* __restrict__ gcur,
                                                  const unsigned* __restrict__ region,
                                                  const float* __restrict__ W_l,
                                                  const float* __restrict__ b_l,
                                                  const float* __restrict__ W_r,
                                                  float* __restrict__ out) {
    __shared__ float acc[BKT_NODES * 11];    // stride 11 breaks bank aliasing
    __shared__ int lcnt[BKT_NODES];
    __shared__ float sWl[IN_DIM * HIDDEN], sWr[IN_DIM * HIDDEN], sb[HIDDEN];
    int t = threadIdx.x;
    for (int i = t; i < BKT_NODES * 11; i += 512) acc[i] = 0.0f;
    if (t < BKT_NODES) lcnt[t] = 0;
    if (t < IN_DIM * HIDDEN) { sWl[t] = W_l[t]; sWr[t] = W_r[t]; }
    if (t < HIDDEN) sb[t] = b_l[t];
    __syncthreads();

    int b = blockIdx.x;
    int n = min(gcur[b], CAPB);
    const unsigned* reg = region + (size_t)b * CAPB;

    for (int i = t; i < n; i += 512) {
        unsigned e = reg[i];                          // coalesced
        int s = e & 0x1FFFF;
        int local = (e >> 17) & (BKT_NODES - 1);
        const float2* xs = (const float2*)(x + (size_t)s * IN_DIM);  // 8B-aligned (40B rows)
        float2 v0 = xs[0], v1 = xs[1], v2 = xs[2], v3 = xs[3], v4 = xs[4];
        atomicAdd(&lcnt[local], 1);
        float* a = &acc[local * 11];
        atomicAdd(&a[0], v0.x); atomicAdd(&a[1], v0.y);
        atomicAdd(&a[2], v1.x); atomicAdd(&a[3], v1.y);
        atomicAdd(&a[4], v2.x); atomicAdd(&a[5], v2.y);
        atomicAdd(&a[6], v3.x); atomicAdd(&a[7], v3.y);
        atomicAdd(&a[8], v4.x); atomicAdd(&a[9], v4.y);
    }
    __syncthreads();

    if (t < BKT_NODES) {
        int node = b * BKT_NODES + t;
        if (node < N_NODES) {
            float inv = 1.0f / fmaxf((float)lcnt[t], 1.0f);
            const float* xp = x + (size_t)node * IN_DIM;
            float m[IN_DIM], xr[IN_DIM];
#pragma unroll
            for (int k = 0; k < IN_DIM; ++k) {
                m[k] = acc[t * 11 + k] * inv;
                xr[k] = xp[k];
            }
            float o[HIDDEN];
#pragma unroll
            for (int h = 0; h < HIDDEN; ++h) o[h] = sb[h];
#pragma unroll
            for (int k = 0; k < IN_DIM; ++k) {
#pragma unroll
                for (int h = 0; h < HIDDEN; ++h)
                    o[h] += m[k] * sWl[k * HIDDEN + h] + xr[k] * sWr[k * HIDDEN + h];
            }
            float4* op = (float4*)(out + (size_t)node * HIDDEN);  // 64B-aligned per node
            op[0] = make_float4(o[0], o[1], o[2], o[3]);
            op[1] = make_float4(o[4], o[5], o[6], o[7]);
            op[2] = make_float4(o[8], o[9], o[10], o[11]);
            op[3] = make_float4(o[12], o[13], o[14], o[15]);
        }
    }
}

// ---------------- fallback (round-1 style, correct, slow) for tiny ws ----------------
__global__ void sage_scatter_fb(const float* __restrict__ x, const int* __restrict__ src,
                                const int* __restrict__ dst, float* __restrict__ summed,
                                float* __restrict__ counts) {
    int e = blockIdx.x * blockDim.x + threadIdx.x;
    if (e >= N_EDGES) return;
    int s = src[e], d = dst[e];
    if ((unsigned)s >= N_NODES || (unsigned)d >= N_NODES) return;
    const float* xs = x + (size_t)s * IN_DIM;
    float* sm = summed + (size_t)d * IN_DIM;
#pragma unroll
    for (int k = 0; k < IN_DIM; ++k) atomicAdd(&sm[k], xs[k]);
    atomicAdd(&counts[d], 1.0f);
}

__global__ void sage_out_fb(const float* __restrict__ x, const float* __restrict__ summed,
                            const float* __restrict__ counts, const float* __restrict__ W_l,
                            const float* __restrict__ b_l, const float* __restrict__ W_r,
                            float* __restrict__ out) {
    __shared__ float sWl[IN_DIM * HIDDEN], sWr[IN_DIM * HIDDEN], sb[HIDDEN];
    int t = threadIdx.x;
    if (t < IN_DIM * HIDDEN) { sWl[t] = W_l[t]; sWr[t] = W_r[t]; }
    if (t < HIDDEN) sb[t] = b_l[t];
    __syncthreads();
    int tid = blockIdx.x * blockDim.x + t;
    if (tid >= N_NODES * HIDDEN) return;
    int node = tid >> 4, h = tid & (HIDDEN - 1);
    float inv = 1.0f / fmaxf(counts[node], 1.0f);
    const float* sm = summed + (size_t)node * IN_DIM;
    const float* xr = x + (size_t)node * IN_DIM;
    float acc = sb[h];
#pragma unroll
    for (int k = 0; k < IN_DIM; ++k)
        acc += sm[k] * inv * sWl[k * HIDDEN + h] + xr[k] * sWr[k * HIDDEN + h];
    out[tid] = acc;
}

extern "C" void kernel_launch(void* const* d_in, const int* in_sizes, int n_in,
                              void* d_out, int out_size, void* d_ws, size_t ws_size,
                              hipStream_t stream) {
    const float* x   = (const float*)d_in[0];
    const int*   ei  = (const int*)d_in[1];   // [2, E] flat: first E = src, next E = dst
    const float* W_l = (const float*)d_in[2];
    const float* b_l = (const float*)d_in[3];
    const float* W_r = (const float*)d_in[4];
    float* out = (float*)d_out;
    const int* src = ei;
    const int* dst = ei + N_EDGES;

    const size_t need = 1024 * 4 + (size_t)NBKT * CAPB * 4;   // gcur(pad) + region = 28.8 MB

    if (ws_size >= need) {
        int* gcur = (int*)d_ws;
        unsigned* region = (unsigned*)((char*)d_ws + 1024 * 4);

        // only the 391 cursors need zeroing (ws re-poisoned to 0xAA each call)
        hipMemsetAsync(gcur, 0, NBKT * sizeof(int), stream);

        bin_edges<<<NB1, 512, 0, stream>>>(src, dst, gcur, region);
        bucket_out<<<NBKT, 512, 0, stream>>>(x, gcur, region, W_l, b_l, W_r, out);
    } else {
        float* summed = (float*)d_ws;
        float* counts = summed + (size_t)N_NODES * IN_DIM;
        hipMemsetAsync(d_ws, 0, (size_t)(N_NODES * IN_DIM + N_NODES) * sizeof(float), stream);
        int threads = 256;
        int eblocks = (N_EDGES + threads - 1) / threads;
        sage_scatter_fb<<<eblocks, threads, 0, stream>>>(x, src, dst, summed, counts);
        int oblocks = (N_NODES * HIDDEN + threads - 1) / threads;
        sage_out_fb<<<oblocks, threads, 0, stream>>>(x, summed, counts, W_l, b_l, W_r, out);
    }
}

// Round 4
// 572.365 us; speedup vs baseline: 6.2784x; 1.0021x over previous
//
#include <hip/hip_runtime.h>

#define N_NODES 100000
#define N_EDGES 6400000
#define IN_DIM 10
#define HIDDEN 16

#define BKT_SHIFT 8
#define BKT_NODES 256                       // nodes per bucket
#define NBKT 391                            // ceil(100000/256)
#define RBIN 38                             // LDS slots per (block,bucket) in pass 1
#define EPB 10240                           // edges per pass-1 block (mean fill 26.2/bin)
#define NB1 ((N_EDGES + EPB - 1) / EPB)     // 625 blocks
#define CAPB 18432                          // region slots per bucket (mean 16368, +16 sd)
#define SPLIT 4                             // sub-blocks per bucket in pass 2
#define PROW 11                             // 10 feats + count

// ---------------- Pass 1: bin edges by dst bucket (unchanged from R3) ----------------
__global__ __launch_bounds__(512) void bin_edges(const int* __restrict__ src,
                                                 const int* __restrict__ dst,
                                                 int* __restrict__ gcur,
                                                 unsigned* __restrict__ region) {
    __shared__ int lcur[NBKT];
    __shared__ unsigned lbin[NBKT * RBIN];   // 59.4 KB
    for (int b = threadIdx.x; b < NBKT; b += 512) lcur[b] = 0;
    __syncthreads();

    int base = blockIdx.x * EPB;
    int end = min(base + EPB, N_EDGES);
    for (int i = base + (int)threadIdx.x; i < end; i += 512) {
        int s = src[i], d = dst[i];
        if ((unsigned)s >= N_NODES || (unsigned)d >= N_NODES) continue;
        unsigned pack = (unsigned)s | ((unsigned)(d & (BKT_NODES - 1)) << 17);
        int b = d >> BKT_SHIFT;
        int pos = atomicAdd(&lcur[b], 1);            // LDS atomic (cheap)
        if (pos < RBIN) {
            lbin[b * RBIN + pos] = pack;
        } else {
            int g = atomicAdd(&gcur[b], 1);          // rare overflow
            if (g < CAPB) region[(size_t)b * CAPB + g] = pack;
        }
    }
    __syncthreads();

    for (int b = threadIdx.x; b < NBKT; b += 512) {
        int f = min(lcur[b], RBIN);
        if (f > 0) {
            int g = atomicAdd(&gcur[b], f);
            unsigned* dp = region + (size_t)b * CAPB;
#pragma unroll 4
            for (int j = 0; j < f; ++j) {
                int gg = g + j;
                if (gg < CAPB) dp[gg] = lbin[b * RBIN + j];
            }
        }
    }
}

// ---------------- Pass 2: SPLIT sub-blocks per bucket -> partial sums ----------------
// grid (NBKT, SPLIT). Each sub-block accumulates its slice of the bucket's region
// into LDS (stride PROW=11; count lives in slot 10), then writes a feat-major
// partial block: partial[((b*SPLIT+sp)*PROW + k)*BKT_NODES + local]  (coalesced).
__global__ __launch_bounds__(512) void bucket_partial(const float* __restrict__ x,
                                                      const int* __restrict__ gcur,
                                                      const unsigned* __restrict__ region,
                                                      float* __restrict__ partial) {
    __shared__ float acc[BKT_NODES * PROW];   // 11.3 KB
    int t = threadIdx.x;
    for (int i = t; i < BKT_NODES * PROW; i += 512) acc[i] = 0.0f;
    __syncthreads();

    int b = blockIdx.x;
    int sp = blockIdx.y;
    int n = min(gcur[b], CAPB);
    int chunk = (n + SPLIT - 1) / SPLIT;
    int start = sp * chunk;
    int end = min(start + chunk, n);
    const unsigned* reg = region + (size_t)b * CAPB;

    for (int i = start + t; i < end; i += 512) {
        unsigned e = reg[i];                          // coalesced
        int s = e & 0x1FFFF;
        int local = (e >> 17) & (BKT_NODES - 1);
        const float2* xs = (const float2*)(x + (size_t)s * IN_DIM);  // 8B-aligned rows
        float2 v0 = xs[0], v1 = xs[1], v2 = xs[2], v3 = xs[3], v4 = xs[4];
        float* a = &acc[local * PROW];
        atomicAdd(&a[0], v0.x); atomicAdd(&a[1], v0.y);
        atomicAdd(&a[2], v1.x); atomicAdd(&a[3], v1.y);
        atomicAdd(&a[4], v2.x); atomicAdd(&a[5], v2.y);
        atomicAdd(&a[6], v3.x); atomicAdd(&a[7], v3.y);
        atomicAdd(&a[8], v4.x); atomicAdd(&a[9], v4.y);
        atomicAdd(&a[10], 1.0f);
    }
    __syncthreads();

    if (t < BKT_NODES) {
        float* dp = partial + (((size_t)b * SPLIT + sp) * PROW) * BKT_NODES;
#pragma unroll
        for (int k = 0; k < PROW; ++k)
            dp[(size_t)k * BKT_NODES + t] = acc[t * PROW + k];   // coalesced per k
    }
}

// ---------------- Pass 3: combine partials + fused mean/GEMV/bias epilogue ----------------
__global__ __launch_bounds__(512) void combine_out(const float* __restrict__ x,
                                                   const float* __restrict__ partial,
                                                   const float* __restrict__ W_l,
                                                   const float* __restrict__ b_l,
                                                   const float* __restrict__ W_r,
                                                   float* __restrict__ out) {
    __shared__ float sWl[IN_DIM * HIDDEN], sWr[IN_DIM * HIDDEN], sb[HIDDEN];
    int t = threadIdx.x;
    if (t < IN_DIM * HIDDEN) { sWl[t] = W_l[t]; sWr[t] = W_r[t]; }
    if (t < HIDDEN) sb[t] = b_l[t];
    __syncthreads();

    int node = blockIdx.x * 512 + t;
    if (node >= N_NODES) return;
    int b = node >> BKT_SHIFT;
    int local = node & (BKT_NODES - 1);

    float s[PROW];
#pragma unroll
    for (int k = 0; k < PROW; ++k) s[k] = 0.0f;
#pragma unroll
    for (int sp = 0; sp < SPLIT; ++sp) {
        const float* pp = partial + (((size_t)b * SPLIT + sp) * PROW) * BKT_NODES + local;
#pragma unroll
        for (int k = 0; k < PROW; ++k) s[k] += pp[(size_t)k * BKT_NODES];  // coalesced
    }

    float inv = 1.0f / fmaxf(s[10], 1.0f);
    const float* xp = x + (size_t)node * IN_DIM;
    float m[IN_DIM], xr[IN_DIM];
#pragma unroll
    for (int k = 0; k < IN_DIM; ++k) { m[k] = s[k] * inv; xr[k] = xp[k]; }

    float o[HIDDEN];
#pragma unroll
    for (int h = 0; h < HIDDEN; ++h) o[h] = sb[h];
#pragma unroll
    for (int k = 0; k < IN_DIM; ++k) {
#pragma unroll
        for (int h = 0; h < HIDDEN; ++h)
            o[h] += m[k] * sWl[k * HIDDEN + h] + xr[k] * sWr[k * HIDDEN + h];
    }
    float4* op = (float4*)(out + (size_t)node * HIDDEN);
    op[0] = make_float4(o[0], o[1], o[2], o[3]);
    op[1] = make_float4(o[4], o[5], o[6], o[7]);
    op[2] = make_float4(o[8], o[9], o[10], o[11]);
    op[3] = make_float4(o[12], o[13], o[14], o[15]);
}

// ---------------- fallback (round-1 style, correct, slow) for tiny ws ----------------
__global__ void sage_scatter_fb(const float* __restrict__ x, const int* __restrict__ src,
                                const int* __restrict__ dst, float* __restrict__ summed,
                                float* __restrict__ counts) {
    int e = blockIdx.x * blockDim.x + threadIdx.x;
    if (e >= N_EDGES) return;
    int s = src[e], d = dst[e];
    if ((unsigned)s >= N_NODES || (unsigned)d >= N_NODES) return;
    const float* xs = x + (size_t)s * IN_DIM;
    float* sm = summed + (size_t)d * IN_DIM;
#pragma unroll
    for (int k = 0; k < IN_DIM; ++k) atomicAdd(&sm[k], xs[k]);
    atomicAdd(&counts[d], 1.0f);
}

__global__ void sage_out_fb(const float* __restrict__ x, const float* __restrict__ summed,
                            const float* __restrict__ counts, const float* __restrict__ W_l,
                            const float* __restrict__ b_l, const float* __restrict__ W_r,
                            float* __restrict__ out) {
    __shared__ float sWl[IN_DIM * HIDDEN], sWr[IN_DIM * HIDDEN], sb[HIDDEN];
    int t = threadIdx.x;
    if (t < IN_DIM * HIDDEN) { sWl[t] = W_l[t]; sWr[t] = W_r[t]; }
    if (t < HIDDEN) sb[t] = b_l[t];
    __syncthreads();
    int tid = blockIdx.x * blockDim.x + t;
    if (tid >= N_NODES * HIDDEN) return;
    int node = tid >> 4, h = tid & (HIDDEN - 1);
    float inv = 1.0f / fmaxf(counts[node], 1.0f);
    const float* sm = summed + (size_t)node * IN_DIM;
    const float* xr = x + (size_t)node * IN_DIM;
    float acc = sb[h];
#pragma unroll
    for (int k = 0; k < IN_DIM; ++k)
        acc += sm[k] * inv * sWl[k * HIDDEN + h] + xr[k] * sWr[k * HIDDEN + h];
    out[tid] = acc;
}

extern "C" void kernel_launch(void* const* d_in, const int* in_sizes, int n_in,
                              void* d_out, int out_size, void* d_ws, size_t ws_size,
                              hipStream_t stream) {
    const float* x   = (const float*)d_in[0];
    const int*   ei  = (const int*)d_in[1];   // [2, E] flat: first E = src, next E = dst
    const float* W_l = (const float*)d_in[2];
    const float* b_l = (const float*)d_in[3];
    const float* W_r = (const float*)d_in[4];
    float* out = (float*)d_out;
    const int* src = ei;
    const int* dst = ei + N_EDGES;

    const size_t region_off  = 4096;
    const size_t region_sz   = (size_t)NBKT * CAPB * 4;                    // 28.83 MB
    const size_t partial_off = region_off + region_sz;
    const size_t partial_sz  = (size_t)NBKT * SPLIT * PROW * BKT_NODES * 4; // 17.63 MB
    const size_t need = partial_off + partial_sz;                           // ~46.5 MB

    if (ws_size >= need) {
        int* gcur = (int*)d_ws;
        unsigned* region = (unsigned*)((char*)d_ws + region_off);
        float* partial = (float*)((char*)d_ws + partial_off);

        // only the 391 cursors need zeroing (ws re-poisoned to 0xAA each call)
        hipMemsetAsync(gcur, 0, NBKT * sizeof(int), stream);

        bin_edges<<<NB1, 512, 0, stream>>>(src, dst, gcur, region);
        dim3 g2(NBKT, SPLIT);
        bucket_partial<<<g2, 512, 0, stream>>>(x, gcur, region, partial);
        combine_out<<<(N_NODES + 511) / 512, 512, 0, stream>>>(x, partial, W_l, b_l, W_r, out);
    } else {
        float* summed = (float*)d_ws;
        float* counts = summed + (size_t)N_NODES * IN_DIM;
        hipMemsetAsync(d_ws, 0, (size_t)(N_NODES * IN_DIM + N_NODES) * sizeof(float), stream);
        int threads = 256;
        int eblocks = (N_EDGES + threads - 1) / threads;
        sage_scatter_fb<<<eblocks, threads, 0, stream>>>(x, src, dst, summed, counts);
        int oblocks = (N_NODES * HIDDEN + threads - 1) / threads;
        sage_out_fb<<<oblocks, threads, 0, stream>>>(x, summed, counts, W_l, b_l, W_r, out);
    }
}

// Round 5
// 230.686 us; speedup vs baseline: 15.5777x; 2.4811x over previous
//
#include <hip/hip_runtime.h>

#define N_NODES 100000
#define N_EDGES 6400000
#define IN_DIM 10
#define HIDDEN 16

#define BKT_SHIFT 8
#define BKT_NODES 256                       // nodes per bucket
#define NBKT 391                            // ceil(100000/256)
#define RBIN 38                             // LDS slots per (block,bucket) in pass 1
#define EPB 10240                           // edges per pass-1 block
#define NB1 ((N_EDGES + EPB - 1) / EPB)     // 625 blocks
#define CAPB 18432                          // region slots per bucket (mean 16368, +16 sd)
#define SPLIT 4                             // sub-blocks per bucket in pass 2
#define CHUNK ((CAPB + SPLIT - 1) / SPLIT)  // 4608 records max per sub-block
#define PROW 11                             // 10 feats + count

// ---------------- Pass 1: bin edges by dst bucket (unchanged from R3/R4) ----------------
__global__ __launch_bounds__(512) void bin_edges(const int* __restrict__ src,
                                                 const int* __restrict__ dst,
                                                 int* __restrict__ gcur,
                                                 unsigned* __restrict__ region) {
    __shared__ int lcur[NBKT];
    __shared__ unsigned lbin[NBKT * RBIN];   // 59.4 KB
    for (int b = threadIdx.x; b < NBKT; b += 512) lcur[b] = 0;
    __syncthreads();

    int base = blockIdx.x * EPB;
    int end = min(base + EPB, N_EDGES);
    for (int i = base + (int)threadIdx.x; i < end; i += 512) {
        int s = src[i], d = dst[i];
        if ((unsigned)s >= N_NODES || (unsigned)d >= N_NODES) continue;
        unsigned pack = (unsigned)s | ((unsigned)(d & (BKT_NODES - 1)) << 17);
        int b = d >> BKT_SHIFT;
        int pos = atomicAdd(&lcur[b], 1);            // LDS int atomic
        if (pos < RBIN) {
            lbin[b * RBIN + pos] = pack;
        } else {
            int g = atomicAdd(&gcur[b], 1);          // rare overflow
            if (g < CAPB) region[(size_t)b * CAPB + g] = pack;
        }
    }
    __syncthreads();

    for (int b = threadIdx.x; b < NBKT; b += 512) {
        int f = min(lcur[b], RBIN);
        if (f > 0) {
            int g = atomicAdd(&gcur[b], f);
            unsigned* dp = region + (size_t)b * CAPB;
#pragma unroll 4
            for (int j = 0; j < f; ++j) {
                int gg = g + j;
                if (gg < CAPB) dp[gg] = lbin[b * RBIN + j];
            }
        }
    }
}

// ---------------- Pass 2: counting-sort per sub-block, register accumulation ----------------
// grid (NBKT, SPLIT), 512 threads. NO float atomics:
//   hist (1 int LDS atomic/rec) -> wave scan -> scatter (1 int atomic + 1 write/rec)
//   -> thread-pair per local node walks its sorted segment, accumulates in VGPRs.
__global__ __launch_bounds__(512) void bucket_sort_partial(const float* __restrict__ x,
                                                           const int* __restrict__ gcur,
                                                           const unsigned* __restrict__ region,
                                                           float* __restrict__ partial) {
    __shared__ unsigned sorted[CHUNK];       // 18.4 KB: src ids grouped by local dst
    __shared__ int offs[BKT_NODES + 1];
    __shared__ int cursor[BKT_NODES];
    __shared__ int hist[BKT_NODES];

    int t = threadIdx.x;
    if (t < BKT_NODES) hist[t] = 0;
    __syncthreads();

    int b = blockIdx.x;
    int sp = blockIdx.y;
    int n = min(gcur[b], CAPB);
    int chunk = (n + SPLIT - 1) / SPLIT;
    int start = sp * chunk;
    int end = min(start + chunk, n);
    const unsigned* reg = region + (size_t)b * CAPB;

    // Phase 1: histogram of local dst (coalesced region read, L2-warm on 2nd pass)
    for (int i = start + t; i < end; i += 512) {
        int local = (reg[i] >> 17) & (BKT_NODES - 1);
        atomicAdd(&hist[local], 1);
    }
    __syncthreads();

    // Phase 2: exclusive prefix sum of 256 counters on wave 0 (4 per lane + shfl scan)
    if (t < 64) {
        int base4 = t * 4;
        int h0 = hist[base4], h1 = hist[base4 + 1], h2 = hist[base4 + 2], h3 = hist[base4 + 3];
        int sum4 = h0 + h1 + h2 + h3;
        int run = sum4;
#pragma unroll
        for (int o = 1; o < 64; o <<= 1) {
            int v = __shfl_up(run, o, 64);
            if (t >= o) run += v;
        }
        int excl = run - sum4;
        offs[base4] = excl;
        offs[base4 + 1] = excl + h0;
        offs[base4 + 2] = excl + h0 + h1;
        offs[base4 + 3] = excl + h0 + h1 + h2;
        cursor[base4] = excl;
        cursor[base4 + 1] = excl + h0;
        cursor[base4 + 2] = excl + h0 + h1;
        cursor[base4 + 3] = excl + h0 + h1 + h2;
        if (t == 63) offs[BKT_NODES] = excl + sum4;
    }
    __syncthreads();

    // Phase 3: scatter src ids into per-node segments
    for (int i = start + t; i < end; i += 512) {
        unsigned e = reg[i];
        int local = (e >> 17) & (BKT_NODES - 1);
        int pos = atomicAdd(&cursor[local], 1);
        sorted[pos] = e & 0x1FFFF;
    }
    __syncthreads();

    // Phase 4: thread pair (2l, 2l+1) accumulates node l's segment in registers
    int local = t >> 1;
    int half = t & 1;
    int s0 = offs[local];
    int s1 = offs[local + 1];
    float acc[IN_DIM];
#pragma unroll
    for (int k = 0; k < IN_DIM; ++k) acc[k] = 0.0f;
    float cnt = 0.0f;
    for (int i = s0 + half; i < s1; i += 2) {
        int s = sorted[i];
        const float2* xs = (const float2*)(x + (size_t)s * IN_DIM);
        float2 v0 = xs[0], v1 = xs[1], v2 = xs[2], v3 = xs[3], v4 = xs[4];
        acc[0] += v0.x; acc[1] += v0.y;
        acc[2] += v1.x; acc[3] += v1.y;
        acc[4] += v2.x; acc[5] += v2.y;
        acc[6] += v3.x; acc[7] += v3.y;
        acc[8] += v4.x; acc[9] += v4.y;
        cnt += 1.0f;
    }
    // combine the pair (adjacent lanes, same wave)
#pragma unroll
    for (int k = 0; k < IN_DIM; ++k) acc[k] += __shfl_xor(acc[k], 1, 64);
    cnt += __shfl_xor(cnt, 1, 64);

    // Phase 5: feat-major partial write (even threads; consecutive locals -> coalesced-ish)
    if (half == 0) {
        float* dp = partial + (((size_t)b * SPLIT + sp) * PROW) * BKT_NODES;
#pragma unroll
        for (int k = 0; k < IN_DIM; ++k) dp[(size_t)k * BKT_NODES + local] = acc[k];
        dp[(size_t)10 * BKT_NODES + local] = cnt;
    }
}

// ---------------- Pass 3: combine partials + fused mean/GEMV/bias (unchanged) ----------------
__global__ __launch_bounds__(512) void combine_out(const float* __restrict__ x,
                                                   const float* __restrict__ partial,
                                                   const float* __restrict__ W_l,
                                                   const float* __restrict__ b_l,
                                                   const float* __restrict__ W_r,
                                                   float* __restrict__ out) {
    __shared__ float sWl[IN_DIM * HIDDEN], sWr[IN_DIM * HIDDEN], sb[HIDDEN];
    int t = threadIdx.x;
    if (t < IN_DIM * HIDDEN) { sWl[t] = W_l[t]; sWr[t] = W_r[t]; }
    if (t < HIDDEN) sb[t] = b_l[t];
    __syncthreads();

    int node = blockIdx.x * 512 + t;
    if (node >= N_NODES) return;
    int b = node >> BKT_SHIFT;
    int local = node & (BKT_NODES - 1);

    float s[PROW];
#pragma unroll
    for (int k = 0; k < PROW; ++k) s[k] = 0.0f;
#pragma unroll
    for (int sp = 0; sp < SPLIT; ++sp) {
        const float* pp = partial + (((size_t)b * SPLIT + sp) * PROW) * BKT_NODES + local;
#pragma unroll
        for (int k = 0; k < PROW; ++k) s[k] += pp[(size_t)k * BKT_NODES];  // coalesced
    }

    float inv = 1.0f / fmaxf(s[10], 1.0f);
    const float* xp = x + (size_t)node * IN_DIM;
    float m[IN_DIM], xr[IN_DIM];
#pragma unroll
    for (int k = 0; k < IN_DIM; ++k) { m[k] = s[k] * inv; xr[k] = xp[k]; }

    float o[HIDDEN];
#pragma unroll
    for (int h = 0; h < HIDDEN; ++h) o[h] = sb[h];
#pragma unroll
    for (int k = 0; k < IN_DIM; ++k) {
#pragma unroll
        for (int h = 0; h < HIDDEN; ++h)
            o[h] += m[k] * sWl[k * HIDDEN + h] + xr[k] * sWr[k * HIDDEN + h];
    }
    float4* op = (float4*)(out + (size_t)node * HIDDEN);
    op[0] = make_float4(o[0], o[1], o[2], o[3]);
    op[1] = make_float4(o[4], o[5], o[6], o[7]);
    op[2] = make_float4(o[8], o[9], o[10], o[11]);
    op[3] = make_float4(o[12], o[13], o[14], o[15]);
}

// ---------------- fallback (round-1 style, correct, slow) for tiny ws ----------------
__global__ void sage_scatter_fb(const float* __restrict__ x, const int* __restrict__ src,
                                const int* __restrict__ dst, float* __restrict__ summed,
                                float* __restrict__ counts) {
    int e = blockIdx.x * blockDim.x + threadIdx.x;
    if (e >= N_EDGES) return;
    int s = src[e], d = dst[e];
    if ((unsigned)s >= N_NODES || (unsigned)d >= N_NODES) return;
    const float* xs = x + (size_t)s * IN_DIM;
    float* sm = summed + (size_t)d * IN_DIM;
#pragma unroll
    for (int k = 0; k < IN_DIM; ++k) atomicAdd(&sm[k], xs[k]);
    atomicAdd(&counts[d], 1.0f);
}

__global__ void sage_out_fb(const float* __restrict__ x, const float* __restrict__ summed,
                            const float* __restrict__ counts, const float* __restrict__ W_l,
                            const float* __restrict__ b_l, const float* __restrict__ W_r,
                            float* __restrict__ out) {
    __shared__ float sWl[IN_DIM * HIDDEN], sWr[IN_DIM * HIDDEN], sb[HIDDEN];
    int t = threadIdx.x;
    if (t < IN_DIM * HIDDEN) { sWl[t] = W_l[t]; sWr[t] = W_r[t]; }
    if (t < HIDDEN) sb[t] = b_l[t];
    __syncthreads();
    int tid = blockIdx.x * blockDim.x + t;
    if (tid >= N_NODES * HIDDEN) return;
    int node = tid >> 4, h = tid & (HIDDEN - 1);
    float inv = 1.0f / fmaxf(counts[node], 1.0f);
    const float* sm = summed + (size_t)node * IN_DIM;
    const float* xr = x + (size_t)node * IN_DIM;
    float acc = sb[h];
#pragma unroll
    for (int k = 0; k < IN_DIM; ++k)
        acc += sm[k] * inv * sWl[k * HIDDEN + h] + xr[k] * sWr[k * HIDDEN + h];
    out[tid] = acc;
}

extern "C" void kernel_launch(void* const* d_in, const int* in_sizes, int n_in,
                              void* d_out, int out_size, void* d_ws, size_t ws_size,
                              hipStream_t stream) {
    const float* x   = (const float*)d_in[0];
    const int*   ei  = (const int*)d_in[1];   // [2, E] flat: first E = src, next E = dst
    const float* W_l = (const float*)d_in[2];
    const float* b_l = (const float*)d_in[3];
    const float* W_r = (const float*)d_in[4];
    float* out = (float*)d_out;
    const int* src = ei;
    const int* dst = ei + N_EDGES;

    const size_t region_off  = 4096;
    const size_t region_sz   = (size_t)NBKT * CAPB * 4;                     // 28.83 MB
    const size_t partial_off = region_off + region_sz;
    const size_t partial_sz  = (size_t)NBKT * SPLIT * PROW * BKT_NODES * 4; // 17.63 MB
    const size_t need = partial_off + partial_sz;                           // ~46.5 MB

    if (ws_size >= need) {
        int* gcur = (int*)d_ws;
        unsigned* region = (unsigned*)((char*)d_ws + region_off);
        float* partial = (float*)((char*)d_ws + partial_off);

        hipMemsetAsync(gcur, 0, NBKT * sizeof(int), stream);

        bin_edges<<<NB1, 512, 0, stream>>>(src, dst, gcur, region);
        dim3 g2(NBKT, SPLIT);
        bucket_sort_partial<<<g2, 512, 0, stream>>>(x, gcur, region, partial);
        combine_out<<<(N_NODES + 511) / 512, 512, 0, stream>>>(x, partial, W_l, b_l, W_r, out);
    } else {
        float* summed = (float*)d_ws;
        float* counts = summed + (size_t)N_NODES * IN_DIM;
        hipMemsetAsync(d_ws, 0, (size_t)(N_NODES * IN_DIM + N_NODES) * sizeof(float), stream);
        int threads = 256;
        int eblocks = (N_EDGES + threads - 1) / threads;
        sage_scatter_fb<<<eblocks, threads, 0, stream>>>(x, src, dst, summed, counts);
        int oblocks = (N_NODES * HIDDEN + threads - 1) / threads;
        sage_out_fb<<<oblocks, threads, 0, stream>>>(x, summed, counts, W_l, b_l, W_r, out);
    }
}